// Round 2
// baseline (280.289 us; speedup 1.0000x reference)
//
#include <hip/hip_runtime.h>

// ContourIntegrationLayer: depthwise 3x3 conv, center tap masked to 0,
// SAME padding, + residual. x: [B,H,W,C] fp32 NHWC, kernel: [3,3,C] fp32.
// B=32 H=56 W=56 C=256.
//
// R1: XCD-aware block swizzle (kept).
// R2: vertical rolling window, P=14 rows/thread. Landed 1.3x not 4x:
//     VGPR=48 proved the compiler rematerialized the 8 kernel taps from L1
//     every iteration (intended live set was 68+ regs). Both R1 and R2 sit
//     at the same ~17-19 TB/s L1-return ceiling -> L1-bound on redundancy.
// R3: contribution pipeline. Each loaded row immediately produces its three
//     row-contributions (T->out y+1, M->out y, B->out y-1) into two pending
//     accumulators, then dies. Live set: 8 taps + 3 row vecs + 2 accs ~ 60
//     VGPR -> fits 7 waves/SIMD. Taps pinned in registers via asm keep-alive
//     so rematerialization cannot recur. Loads/output: ~3.4, all x-reads.

#define BB 32
#define HH 56
#define WW 56
#define C4 64            // 256 channels / 4 per float4
#define NXCD 8
#define P 14             // output rows per thread (56 = 4*14)
#define NHC 4            // h-chunks
#define ROWSTR (WW * C4) // float4 stride between image rows = 3584

// Pin a float4 in VGPRs: compiler cannot rematerialize past this.
#define KEEP4(v) asm volatile("" : "+v"((v).x), "+v"((v).y), "+v"((v).z), "+v"((v).w))

// T(y) = k0*L + k1*C + k2*R   -> contribution to output row y+1
#define CALC_T(d)                                   \
    (d).x = k0.x*Lv.x + k1.x*Cv.x + k2.x*Rv.x;      \
    (d).y = k0.y*Lv.y + k1.y*Cv.y + k2.y*Rv.y;      \
    (d).z = k0.z*Lv.z + k1.z*Cv.z + k2.z*Rv.z;      \
    (d).w = k0.w*Lv.w + k1.w*Cv.w + k2.w*Rv.w;

// M(y) = C (residual) + k3*L + k5*R  -> contribution to output row y
#define ADD_M(d)                                    \
    (d).x += Cv.x + k3.x*Lv.x + k5.x*Rv.x;          \
    (d).y += Cv.y + k3.y*Lv.y + k5.y*Rv.y;          \
    (d).z += Cv.z + k3.z*Lv.z + k5.z*Rv.z;          \
    (d).w += Cv.w + k3.w*Lv.w + k5.w*Rv.w;

// B(y) = k6*L + k7*C + k8*R  -> contribution to output row y-1
#define ADD_B(d)                                    \
    (d).x += k6.x*Lv.x + k7.x*Cv.x + k8.x*Rv.x;     \
    (d).y += k6.y*Lv.y + k7.y*Cv.y + k8.y*Rv.y;     \
    (d).z += k6.z*Lv.z + k7.z*Cv.z + k8.z*Rv.z;     \
    (d).w += k6.w*Lv.w + k7.w*Cv.w + k8.w*Rv.w;

#define LOADROW(y)                                  \
    {                                               \
        const float4* p = xb + (y) * ROWSTR;        \
        Cv = p[0];                                  \
        Lv = wl ? p[-C4] : zero;                    \
        Rv = wr ? p[ C4] : zero;                    \
    }

__global__ __launch_bounds__(256, 7) void contour_kernel(
    const float4* __restrict__ x,     // [B*H*W*C4]
    const float4* __restrict__ kern,  // [9*C4]
    float4* __restrict__ out)         // [B*H*W*C4]
{
    // XCD swizzle: hardware assigns blockIdx.x -> XCD (blockIdx.x % 8).
    // Remap so each XCD owns a contiguous chunk (4 whole images).
    const int nblocks = gridDim.x;          // 1792, divisible by 8
    const int per_xcd = nblocks / NXCD;     // 224
    const int xcd     = blockIdx.x % NXCD;
    const int local   = blockIdx.x / NXCD;
    const int blk     = xcd * per_xcd + local;

    int idx = blk * blockDim.x + threadIdx.x;
    int c4 = idx & (C4 - 1);
    int s  = idx >> 6;            // strip: ((b*NHC + hc)*WW + w)
    int w  = s % WW;              // constant per wave
    int t  = s / WW;
    int hc = t & (NHC - 1);       // constant per block
    int b  = t >> 2;              // constant per block

    const float4 zero = make_float4(0.f, 0.f, 0.f, 0.f);

    // Kernel taps (center tap k4 masked out). Pinned so they stay resident.
    const float4* kp = kern + c4;
    float4 k0 = kp[0 * C4], k1 = kp[1 * C4], k2 = kp[2 * C4];
    float4 k3 = kp[3 * C4],                  k5 = kp[5 * C4];
    float4 k6 = kp[6 * C4], k7 = kp[7 * C4], k8 = kp[8 * C4];
    KEEP4(k0); KEEP4(k1); KEEP4(k2); KEEP4(k3);
    KEEP4(k5); KEEP4(k6); KEEP4(k7); KEEP4(k8);

    const int h0 = hc * P;
    const float4* xb = x   + (size_t)(b * HH) * ROWSTR + w * C4 + c4;
    float4*       ob = out + (size_t)(b * HH) * ROWSTR + w * C4 + c4;

    const bool wl = (w > 0);        // wave-uniform
    const bool wr = (w < WW - 1);   // wave-uniform

    float4 Lv, Cv, Rv;  // current input row (w-1, w, w+1)
    float4 pA;          // pending partial for output y-1
    float4 pB;          // pending partial for output y

    // step 0: y = h0-1 (top halo row; only its T contribution is needed)
    if (h0 > 0) {                   // block-uniform branch
        LOADROW(h0 - 1);
        CALC_T(pB);
    } else {
        pB = zero;
    }

    // step 1: y = h0 (output h0-1 belongs to the strip above -> no store)
    LOADROW(h0);
    ADD_M(pB);                      // pB = out(h0) partial: T(h0-1)+M(h0)+x
    pA = pB;
    CALC_T(pB);                     // pB = T(h0) for out(h0+1)

    // steps 2..14: y = h0+1 .. h0+13 (full pipeline)
    #pragma unroll
    for (int j = 1; j <= P - 1; ++j) {
        const int y = h0 + j;
        LOADROW(y);
        ADD_B(pA);                  // completes out(y-1)
        ob[(y - 1) * ROWSTR] = pA;
        ADD_M(pB);                  // pB = out(y) partial
        pA = pB;
        CALC_T(pB);                 // pB = T(y) for out(y+1)
    }

    // step 15: y = h0+14 (bottom halo row; only its B contribution)
    if (h0 + P < HH) {              // block-uniform branch
        LOADROW(h0 + P);
        ADD_B(pA);
    }
    ob[(h0 + P - 1) * ROWSTR] = pA;
}

extern "C" void kernel_launch(void* const* d_in, const int* in_sizes, int n_in,
                              void* d_out, int out_size, void* d_ws, size_t ws_size,
                              hipStream_t stream) {
    const float4* x    = (const float4*)d_in[0];
    const float4* kern = (const float4*)d_in[1];
    float4* out        = (float4*)d_out;

    const int total = BB * NHC * WW * C4;           // 458,752 threads
    const int block = 256;
    const int grid  = (total + block - 1) / block;  // 1792 blocks (8*224)
    contour_kernel<<<grid, block, 0, stream>>>(x, kern, out);
}

// Round 3
// 204.030 us; speedup vs baseline: 1.3738x; 1.3738x over previous
//
#include <hip/hip_runtime.h>

// ContourIntegrationLayer: depthwise 3x3 conv, center tap masked to 0,
// SAME padding, + residual. x: [B,H,W,C] fp32 NHWC, kernel: [3,3,C] fp32.
// B=32 H=56 W=56 C=256.
//
// R1: XCD-aware block swizzle (kept).
// R2: vertical rolling window P=14. Only 1.3x: compiler capped at 48 VGPR
//     (targets <=64 for 8 waves/SIMD) and re-fetched the taps from L1 every
//     row -> still L1-bound on redundancy.
// R3: asm-pinned taps. Backfired: pins blocked rematerialization, allocator
//     SPILLED to scratch (VGPR=36, FETCH +81MB, WRITE +40MB, 2x slower).
// R4: stop fighting the allocator. Taps live in LDS (8KB/block, staged
//     once): if the compiler re-reads them per row it's a ds_read_b128 at
//     69 TB/s, not an L1 vmem fetch, and spilling is never chosen because
//     LDS-remat is always available. Contribution pipeline kept (minimum
//     live set: 3 row vecs + 2 accs). unroll 1 + incremental pointers keep
//     the genuine live set ~50 VGPR. Global loads/output: 3. Stores: 1.

#define BB 32
#define HH 56
#define WW 56
#define C4 64            // 256 channels / 4 per float4
#define NXCD 8
#define P 14             // output rows per thread (56 = 4*14)
#define NHC 4            // h-chunks
#define ROWSTR (WW * C4) // float4 stride between image rows = 3584

// T(y) = k0*L + k1*C + k2*R   -> contribution to output row y+1
#define CALC_T(d)                                       \
    {                                                   \
        float4 K0 = kl[0*C4], K1 = kl[1*C4], K2 = kl[2*C4]; \
        (d).x = K0.x*Lv.x + K1.x*Cv.x + K2.x*Rv.x;      \
        (d).y = K0.y*Lv.y + K1.y*Cv.y + K2.y*Rv.y;      \
        (d).z = K0.z*Lv.z + K1.z*Cv.z + K2.z*Rv.z;      \
        (d).w = K0.w*Lv.w + K1.w*Cv.w + K2.w*Rv.w;      \
    }

// M(y) = C (residual) + k3*L + k5*R  -> contribution to output row y
#define ADD_M(d)                                        \
    {                                                   \
        float4 K3 = kl[3*C4], K5 = kl[5*C4];            \
        (d).x += Cv.x + K3.x*Lv.x + K5.x*Rv.x;          \
        (d).y += Cv.y + K3.y*Lv.y + K5.y*Rv.y;          \
        (d).z += Cv.z + K3.z*Lv.z + K5.z*Rv.z;          \
        (d).w += Cv.w + K3.w*Lv.w + K5.w*Rv.w;          \
    }

// B(y) = k6*L + k7*C + k8*R  -> contribution to output row y-1
#define ADD_B(d)                                        \
    {                                                   \
        float4 K6 = kl[6*C4], K7 = kl[7*C4], K8 = kl[8*C4]; \
        (d).x += K6.x*Lv.x + K7.x*Cv.x + K8.x*Rv.x;     \
        (d).y += K6.y*Lv.y + K7.y*Cv.y + K8.y*Rv.y;     \
        (d).z += K6.z*Lv.z + K7.z*Cv.z + K8.z*Rv.z;     \
        (d).w += K6.w*Lv.w + K7.w*Cv.w + K8.w*Rv.w;     \
    }

#define LOADROW(p)                                      \
    {                                                   \
        Cv = (p)[0];                                    \
        Lv = wl ? (p)[-C4] : zero;                      \
        Rv = wr ? (p)[ C4] : zero;                      \
    }

__global__ __launch_bounds__(256, 7) void contour_kernel(
    const float4* __restrict__ x,     // [B*H*W*C4]
    const float4* __restrict__ kern,  // [9*C4]
    float4* __restrict__ out)         // [B*H*W*C4]
{
    // Kernel taps staged to LDS once per block (9 taps x 64 c4 x 16 B).
    __shared__ float4 lds_k[9 * C4];
    for (int i = threadIdx.x; i < 9 * C4; i += 256)
        lds_k[i] = kern[i];

    // XCD swizzle: hardware assigns blockIdx.x -> XCD (blockIdx.x % 8).
    // Remap so each XCD owns a contiguous chunk (4 whole images).
    const int nblocks = gridDim.x;          // 1792, divisible by 8
    const int per_xcd = nblocks / NXCD;     // 224
    const int xcd     = blockIdx.x % NXCD;
    const int local   = blockIdx.x / NXCD;
    const int blk     = xcd * per_xcd + local;

    int idx = blk * blockDim.x + threadIdx.x;
    int c4 = idx & (C4 - 1);      // == lane id
    int s  = idx >> 6;            // strip: ((b*NHC + hc)*WW + w)
    int w  = s % WW;              // constant per wave
    int t  = s / WW;
    int hc = t & (NHC - 1);       // constant per block
    int b  = t >> 2;              // constant per block

    __syncthreads();

    const float4 zero = make_float4(0.f, 0.f, 0.f, 0.f);
    const float4* kl = lds_k + c4;          // tap t at kl[t*C4]

    const int h0 = hc * P;
    const float4* xr = x   + (size_t)(b * HH + h0) * ROWSTR + w * C4 + c4;
    float4*       op = out + (size_t)(b * HH + h0) * ROWSTR + w * C4 + c4;

    const bool wl = (w > 0);        // wave-uniform
    const bool wr = (w < WW - 1);   // wave-uniform

    float4 Lv, Cv, Rv;  // current input row (w-1, w, w+1)
    float4 pA;          // pending partial for output y-1
    float4 pB;          // pending partial for output y

    // step 0: y = h0-1 (top halo row; only its T contribution is needed)
    if (h0 > 0) {                   // block-uniform branch
        const float4* p = xr - ROWSTR;
        LOADROW(p);
        CALC_T(pB);
    } else {
        pB = zero;
    }

    // step 1: y = h0
    LOADROW(xr);
    ADD_M(pB);                      // pB = out(h0) partial: T(h0-1)+M(h0)+x
    pA = pB;
    CALC_T(pB);                     // pB = T(h0) for out(h0+1)

    // steps 2..14: y = h0+1 .. h0+13 (steady-state pipeline)
    const float4* xp = xr + ROWSTR;
    #pragma unroll 1
    for (int j = 1; j <= P - 1; ++j) {
        LOADROW(xp);
        xp += ROWSTR;
        ADD_B(pA);                  // completes out(y-1)
        *op = pA;
        op += ROWSTR;
        ADD_M(pB);                  // pB = out(y) partial
        pA = pB;
        CALC_T(pB);                 // pB = T(y) for out(y+1)
    }

    // step 15: y = h0+14 (bottom halo row; only its B contribution)
    if (h0 + P < HH) {              // block-uniform branch
        LOADROW(xp);
        ADD_B(pA);
    }
    *op = pA;                       // out(h0+13)
}

extern "C" void kernel_launch(void* const* d_in, const int* in_sizes, int n_in,
                              void* d_out, int out_size, void* d_ws, size_t ws_size,
                              hipStream_t stream) {
    const float4* x    = (const float4*)d_in[0];
    const float4* kern = (const float4*)d_in[1];
    float4* out        = (float4*)d_out;

    const int total = BB * NHC * WW * C4;           // 458,752 threads
    const int block = 256;
    const int grid  = (total + block - 1) / block;  // 1792 blocks (8*224)
    contour_kernel<<<grid, block, 0, stream>>>(x, kern, out);
}